// Round 1
// baseline (204.178 us; speedup 1.0000x reference)
//
#include <hip/hip_runtime.h>
#include <math.h>

// Problem constants
#define S_  2048
#define D_  1024
// H=8, D_HEAD=32, D_HEAD_OUT=128, NCOL1=256, NCOL2=1024, M=65536

typedef __attribute__((ext_vector_type(8))) short short8;
typedef __attribute__((ext_vector_type(4))) float f32x4;

static __device__ __forceinline__ unsigned short f2bf(float x) {
    // RTNE float -> bf16 (inputs are well-behaved, no NaN handling needed)
    unsigned int u = __builtin_bit_cast(unsigned int, x);
    u += 0x7fffu + ((u >> 16) & 1u);
    return (unsigned short)(u >> 16);
}
static __device__ __forceinline__ float bf2f(unsigned short s) {
    unsigned int u = ((unsigned int)s) << 16;
    return __builtin_bit_cast(float, u);
}

__device__ __forceinline__ void gl_lds16(const void* g, void* l) {
    __builtin_amdgcn_global_load_lds(
        (const __attribute__((address_space(1))) unsigned int*)g,
        (__attribute__((address_space(3))) unsigned int*)l, 16, 0, 0);
}

// ---------------------------------------------------------------------------
// Pack w1 (fp32 [8][1024][32]) into MFMA B-fragment order, bf16:
//   w1p[((ks*16 + cf)*64 + lane)*8 + r]  = B[k][col]
//   col = cf*16 + (lane&15) (col = h*32+e), k = ks*32 + (lane>>4)*8 + r (k = d)
// 32 ksteps * 16 colfrags * 64 lanes * 8 = 256K bf16 = 512 KB
__global__ void prep_w1(const float* __restrict__ w1, short* __restrict__ w1p) {
    int tid = blockIdx.x * 256 + threadIdx.x;   // 32768 threads
    int lane = tid & 63;
    int fragid = tid >> 6;
    int cf = fragid & 15, ks = fragid >> 4;
    int col = cf * 16 + (lane & 15);
    int h = col >> 5, e = col & 31;
    int d0 = ks * 32 + (lane >> 4) * 8;
    short8 v;
#pragma unroll
    for (int r = 0; r < 8; ++r)
        v[r] = (short)f2bf(w1[((size_t)h * D_ + (d0 + r)) * 32 + e]);
    *(short8*)(w1p + (size_t)tid * 8) = v;
}

// Pack w2 (fp32 [8][32][128]) into B-fragment order, bf16:
//   w2p[((h*8 + cf2)*64 + lane)*8 + r]; col=o=cf2*16+(lane&15), k=e=(lane>>4)*8+r
// 8 heads * 8 colfrags * 64 * 8 = 32K bf16 = 64 KB
__global__ void prep_w2(const float* __restrict__ w2, short* __restrict__ w2p) {
    int tid = blockIdx.x * 256 + threadIdx.x;   // 4096 threads
    int lane = tid & 63;
    int fragid = tid >> 6;
    int cf2 = fragid & 7, h = fragid >> 3;
    int o = cf2 * 16 + (lane & 15);
    int e0 = (lane >> 4) * 8;
    short8 v;
#pragma unroll
    for (int r = 0; r < 8; ++r)
        v[r] = (short)f2bf(w2[((size_t)h * 32 + (e0 + r)) * 128 + o]);
    *(short8*)(w2p + (size_t)tid * 8) = v;
}

// ---------------------------------------------------------------------------
// Fused: GEMM1 (feat @ w1 + b1) -> gelu -> GEMM2 (@ w2 + b2) -> exp -> E (bf16)
// Block = 256 threads (4 waves), 64 rows per block. Wave w: rows w*16..w*16+15.
__global__ __launch_bounds__(256) void fused1(
        const float* __restrict__ feat,
        const short* __restrict__ w1p,
        const short* __restrict__ w2p,
        const float* __restrict__ b1,
        const float* __restrict__ b2,
        unsigned short* __restrict__ E)
{
    __shared__ __align__(16) char lds[66816];
    short* Bbuf = (short*)lds;                       // [2][8192] shorts (2x16KB)
    short* hact = (short*)(lds + 33024);             // [64][264] bf16 (+16B row pad)
    unsigned short* Est = (unsigned short*)lds;      // [16][1032] bf16 (reuses Bbuf)

    const int tid = threadIdx.x;
    const int wv = tid >> 6;
    const int lane = tid & 63;
    const int lr = lane & 15;       // A row / C col within fragment
    const int lg = lane >> 4;       // k-group
    const size_t m0 = (size_t)blockIdx.x * 64;

    // A fragment source: row = m0 + wv*16 + lr, k = ks*32 + lg*8 .. +7 (fp32)
    const f32x4* Arow = (const f32x4*)(feat + (m0 + (size_t)(wv * 16 + lr)) * D_);

    const f32x4 vzero = {0.f, 0.f, 0.f, 0.f};
    f32x4 acc[16];
#pragma unroll
    for (int i = 0; i < 16; ++i) acc[i] = vzero;

    auto stageB = [&](int buf_, int ks_) {
#pragma unroll
        for (int j = 0; j < 4; ++j)
            gl_lds16(w1p + (size_t)ks_ * 8192 + (size_t)(j * 256 + tid) * 8,
                     Bbuf + buf_ * 8192 + (j * 256 + wv * 64) * 8);
    };

    // ---- GEMM1: 32 ksteps of K=32, double-buffered B in LDS ----
    stageB(0, 0);
    int buf = 0;
    for (int ks = 0; ks < 32; ++ks) {
        __syncthreads();                     // drains vmcnt: B(ks) staged; prev reads done
        if (ks + 1 < 32) stageB(buf ^ 1, ks + 1);

        f32x4 a0 = Arow[ks * 8 + lg * 2 + 0];
        f32x4 a1 = Arow[ks * 8 + lg * 2 + 1];
        short8 af;
        af[0] = (short)f2bf(a0.x); af[1] = (short)f2bf(a0.y);
        af[2] = (short)f2bf(a0.z); af[3] = (short)f2bf(a0.w);
        af[4] = (short)f2bf(a1.x); af[5] = (short)f2bf(a1.y);
        af[6] = (short)f2bf(a1.z); af[7] = (short)f2bf(a1.w);

        const short8* Bf = (const short8*)(Bbuf + buf * 8192);
#pragma unroll
        for (int cf = 0; cf < 16; ++cf) {
            short8 bfr = Bf[cf * 64 + lane];
            acc[cf] = __builtin_amdgcn_mfma_f32_16x16x32_bf16(af, bfr, acc[cf], 0, 0, 0);
        }
        buf ^= 1;
    }

    // ---- epilogue 1: + b1, exact-erf gelu, write hact (bf16) to LDS ----
    // C/D layout: col = lane&15, row = (lane>>4)*4 + r   [verified m89/m91]
#pragma unroll
    for (int cf = 0; cf < 16; ++cf) {
        const int col = cf * 16 + lr;           // == h*32 + e == flat b1 index
        const float bias = b1[col];
#pragma unroll
        for (int r = 0; r < 4; ++r) {
            const int row = wv * 16 + lg * 4 + r;
            float x = acc[cf][r] + bias;
            float g = 0.5f * x * (1.0f + erff(x * 0.70710678118654752f));
            hact[row * 264 + col] = (short)f2bf(g);
        }
    }

    // ---- GEMM2 setup: wave wv owns heads {2wv, 2wv+1} = logit cols [wv*256,+256) ----
    short8 bw[16];
    float bias2[16];
#pragma unroll
    for (int cf = 0; cf < 16; ++cf) {
        const int h = 2 * wv + (cf >> 3);
        const int cf2 = cf & 7;
        bw[cf] = *(const short8*)(w2p + ((size_t)(h * 8 + cf2) * 64 + lane) * 8);
        bias2[cf] = b2[h * 128 + cf2 * 16 + lr];
    }
    __syncthreads();   // hact visible; all Bbuf (GEMM1) reads done before Est aliasing

    for (int rf = 0; rf < 4; ++rf) {
        // A frags from hact: row = rf*16 + lr, k(=e) = lg*8..+7, per head
        short8 ah0 = *(const short8*)(hact + (rf * 16 + lr) * 264 + (2 * wv + 0) * 32 + lg * 8);
        short8 ah1 = *(const short8*)(hact + (rf * 16 + lr) * 264 + (2 * wv + 1) * 32 + lg * 8);
#pragma unroll
        for (int cf = 0; cf < 16; ++cf) {
            f32x4 c = vzero;
            c = __builtin_amdgcn_mfma_f32_16x16x32_bf16((cf < 8) ? ah0 : ah1, bw[cf], c, 0, 0, 0);
            const int colL = wv * 256 + (cf >> 3) * 128 + (cf & 7) * 16 + lr;
#pragma unroll
            for (int r = 0; r < 4; ++r) {
                float e = __expf(c[r] + bias2[cf]);   // logits tiny: no max-sub needed
                Est[(lg * 4 + r) * 1032 + colL] = f2bf(e);
            }
        }
        __syncthreads();
        // cooperative coalesced store: 16 rows x 1024 cols bf16 -> E row-major
#pragma unroll
        for (int j = 0; j < 8; ++j) {
            const int idx = j * 256 + tid;
            const int row = idx >> 7;
            const int ch = idx & 127;
            short8 v = *(const short8*)(Est + row * 1032 + ch * 8);
            *(short8*)(E + (m0 + (size_t)(rf * 16 + row)) * 1024 + ch * 8) = v;
        }
        __syncthreads();
    }
}

// ---------------------------------------------------------------------------
// out[b,d] = (sum_s feat[b,s,d] * E[b,s,d]) / (sum_s E[b,s,d])
// grid = 32 b * 16 col-chunks = 512 blocks; thread: col = chunk*64 + (t&63),
// s-quarter q = t>>6; combine 4 partials through LDS.
__global__ __launch_bounds__(256) void finalize(
        const float* __restrict__ feat,
        const unsigned short* __restrict__ E,
        float* __restrict__ out)
{
    const int b = blockIdx.x >> 4;
    const int chunk = blockIdx.x & 15;
    const int t = threadIdx.x;
    const int cl = t & 63;
    const int q = t >> 6;

    const float* fp = feat + ((size_t)b * S_ + (size_t)q * 512) * D_ + chunk * 64 + cl;
    const unsigned short* ep = E + ((size_t)b * S_ + (size_t)q * 512) * 1024 + chunk * 64 + cl;

    float num = 0.f, den = 0.f;
#pragma unroll 8
    for (int i = 0; i < 512; ++i) {
        float f = fp[(size_t)i * D_];
        float e = bf2f(ep[(size_t)i * 1024]);
        num = fmaf(f, e, num);
        den += e;
    }

    __shared__ float sn[256], sd[256];
    sn[t] = num; sd[t] = den;
    __syncthreads();
    if (t < 64) {
        float N  = sn[t] + sn[t + 64] + sn[t + 128] + sn[t + 192];
        float Dn = sd[t] + sd[t + 64] + sd[t + 128] + sd[t + 192];
        out[(size_t)b * D_ + chunk * 64 + t] = N / Dn;
    }
}

// ---------------------------------------------------------------------------
extern "C" void kernel_launch(void* const* d_in, const int* in_sizes, int n_in,
                              void* d_out, int out_size, void* d_ws, size_t ws_size,
                              hipStream_t stream) {
    (void)in_sizes; (void)n_in; (void)out_size; (void)ws_size;
    const float* feat = (const float*)d_in[0];
    const float* w1   = (const float*)d_in[1];
    const float* b1   = (const float*)d_in[2];
    const float* w2   = (const float*)d_in[3];
    const float* b2   = (const float*)d_in[4];
    float* out = (float*)d_out;

    char* ws = (char*)d_ws;
    unsigned short* E = (unsigned short*)ws;                       // 128 MiB
    short* w1p = (short*)(ws + 134217728ull);                      // 512 KiB
    short* w2p = (short*)(ws + 134217728ull + 524288ull);          // 64 KiB

    prep_w1<<<128, 256, 0, stream>>>(w1, w1p);
    prep_w2<<<16, 256, 0, stream>>>(w2, w2p);
    fused1<<<1024, 256, 0, stream>>>(feat, w1p, w2p, b1, b2, E);
    finalize<<<512, 256, 0, stream>>>(feat, E, out);
}

// Round 2
// 174.206 us; speedup vs baseline: 1.1720x; 1.1720x over previous
//
#include <hip/hip_runtime.h>
#include <math.h>

// Problem constants: B=32, S=2048, D=1024, H=8, D_HEAD=32, D_HEAD_OUT=128
#define S_  2048
#define D_  1024
// M = 65536 rows, GEMM1: [M,1024]@[1024,256], GEMM2 per-head K=32 -> [M,1024] logits

typedef __attribute__((ext_vector_type(8))) short short8;
typedef __attribute__((ext_vector_type(4))) float f32x4;

static __device__ __forceinline__ unsigned short f2bf(float x) {
    unsigned int u = __builtin_bit_cast(unsigned int, x);
    u += 0x7fffu + ((u >> 16) & 1u);
    return (unsigned short)(u >> 16);
}

__device__ __forceinline__ void gl_lds16(const void* g, void* l) {
    __builtin_amdgcn_global_load_lds(
        (const __attribute__((address_space(1))) unsigned int*)g,
        (__attribute__((address_space(3))) unsigned int*)l, 16, 0, 0);
}

// ---------------------------------------------------------------------------
// Pack w1 (fp32 [8][1024][32]) into MFMA B-fragment order, bf16:
//   w1p[((ks*16 + cf)*64 + lane)*8 + r];  col=cf*16+(lane&15) (=h*32+e),
//   k = ks*32 + (lane>>4)*8 + r (= d)
__global__ void prep_w1(const float* __restrict__ w1, short* __restrict__ w1p) {
    int tid = blockIdx.x * 256 + threadIdx.x;   // 32768 threads
    int lane = tid & 63;
    int fragid = tid >> 6;
    int cf = fragid & 15, ks = fragid >> 4;
    int col = cf * 16 + (lane & 15);
    int h = col >> 5, e = col & 31;
    int d0 = ks * 32 + (lane >> 4) * 8;
    short8 v;
#pragma unroll
    for (int r = 0; r < 8; ++r)
        v[r] = (short)f2bf(w1[((size_t)h * D_ + (d0 + r)) * 32 + e]);
    *(short8*)(w1p + (size_t)tid * 8) = v;
}

// Pack w2 (fp32 [8][32][128]) into B-fragment order, bf16:
//   w2p[((h*8 + cf2)*64 + lane)*8 + r]; col=o=cf2*16+(lane&15), k=e=(lane>>4)*8+r
__global__ void prep_w2(const float* __restrict__ w2, short* __restrict__ w2p) {
    int tid = blockIdx.x * 256 + threadIdx.x;   // 4096 threads
    int lane = tid & 63;
    int fragid = tid >> 6;
    int cf2 = fragid & 7, h = fragid >> 3;
    int o = cf2 * 16 + (lane & 15);
    int e0 = (lane >> 4) * 8;
    short8 v;
#pragma unroll
    for (int r = 0; r < 8; ++r)
        v[r] = (short)f2bf(w2[((size_t)h * 32 + (e0 + r)) * 128 + o]);
    *(short8*)(w2p + (size_t)tid * 8) = v;
}

// ---------------------------------------------------------------------------
// Fused: GEMM1 -> gelu -> GEMM2 -> exp -> per-column {sum E, sum feat*E}
// partials for this 64-row group. No E materialization.
// Block = 256 threads (4 waves), 64 rows. GEMM1 wave grid 2x2:
// wave (wr,wc) owns rows wr*32+[0,32), cols wc*128+[0,128).
__global__ __launch_bounds__(256, 4) void fused1(
        const float* __restrict__ feat,
        const short* __restrict__ w1p,
        const short* __restrict__ w2p,
        const float* __restrict__ b1,
        const float* __restrict__ b2,
        float* __restrict__ pnum,
        float* __restrict__ pden)
{
    __shared__ __align__(16) char lds[34816];
    short* Bbuf = (short*)lds;                 // [2][8192] shorts (2x16KB)
    short* hact = (short*)lds;                 // [64][264] bf16 (aliases Bbuf)

    const int tid = threadIdx.x;
    const int wv = tid >> 6;
    const int lane = tid & 63;
    const int lr = lane & 15;
    const int lg = lane >> 4;
    const int wr = wv >> 1, wc = wv & 1;
    const size_t m0 = (size_t)blockIdx.x * 64;

    const f32x4* Arow0 = (const f32x4*)(feat + (m0 + (size_t)(wr * 32 + lr)) * D_);
    const f32x4* Arow1 = (const f32x4*)(feat + (m0 + (size_t)(wr * 32 + 16 + lr)) * D_);

    const f32x4 vzero = {0.f, 0.f, 0.f, 0.f};
    f32x4 acc[2][8];
#pragma unroll
    for (int i = 0; i < 2; ++i)
#pragma unroll
        for (int j = 0; j < 8; ++j) acc[i][j] = vzero;

    auto stageB = [&](int buf_, int ks_) {
#pragma unroll
        for (int j = 0; j < 4; ++j)
            gl_lds16(w1p + (size_t)ks_ * 8192 + (size_t)(j * 256 + tid) * 8,
                     Bbuf + buf_ * 8192 + (j * 256 + wv * 64) * 8);
    };

    // ---- GEMM1: 32 ksteps of K=32, B double-buffered in LDS, A prefetched ----
    stageB(0, 0);
    f32x4 p00 = Arow0[lg * 2], p01 = Arow0[lg * 2 + 1];
    f32x4 p10 = Arow1[lg * 2], p11 = Arow1[lg * 2 + 1];
    int buf = 0;
    for (int ks = 0; ks < 32; ++ks) {
        __syncthreads();                 // B(ks) staged; A(ks) prefetch landed
        if (ks + 1 < 32) stageB(buf ^ 1, ks + 1);
        f32x4 a00 = p00, a01 = p01, a10 = p10, a11 = p11;
        if (ks + 1 < 32) {
            const int o = (ks + 1) * 8 + lg * 2;
            p00 = Arow0[o]; p01 = Arow0[o + 1];
            p10 = Arow1[o]; p11 = Arow1[o + 1];
        }
        short8 af0, af1;
        af0[0] = (short)f2bf(a00.x); af0[1] = (short)f2bf(a00.y);
        af0[2] = (short)f2bf(a00.z); af0[3] = (short)f2bf(a00.w);
        af0[4] = (short)f2bf(a01.x); af0[5] = (short)f2bf(a01.y);
        af0[6] = (short)f2bf(a01.z); af0[7] = (short)f2bf(a01.w);
        af1[0] = (short)f2bf(a10.x); af1[1] = (short)f2bf(a10.y);
        af1[2] = (short)f2bf(a10.z); af1[3] = (short)f2bf(a10.w);
        af1[4] = (short)f2bf(a11.x); af1[5] = (short)f2bf(a11.y);
        af1[6] = (short)f2bf(a11.z); af1[7] = (short)f2bf(a11.w);

        const short8* Bf = (const short8*)(Bbuf + buf * 8192);
#pragma unroll
        for (int cf = 0; cf < 8; ++cf) {
            short8 bfr = Bf[(wc * 8 + cf) * 64 + lane];
            acc[0][cf] = __builtin_amdgcn_mfma_f32_16x16x32_bf16(af0, bfr, acc[0][cf], 0, 0, 0);
            acc[1][cf] = __builtin_amdgcn_mfma_f32_16x16x32_bf16(af1, bfr, acc[1][cf], 0, 0, 0);
        }
        buf ^= 1;
    }

    __syncthreads();     // all Bbuf reads done -> safe to overwrite with hact

    // ---- epilogue 1: + b1, exact-erf gelu -> hact (bf16, LDS) ----
    // C/D layout: col = lane&15, row = (lane>>4)*4 + r
#pragma unroll
    for (int rf1 = 0; rf1 < 2; ++rf1)
#pragma unroll
    for (int cf = 0; cf < 8; ++cf) {
        const int col = wc * 128 + cf * 16 + lr;
        const float bias = b1[col];
#pragma unroll
        for (int r = 0; r < 4; ++r) {
            const int row = wr * 32 + rf1 * 16 + lg * 4 + r;
            float x = acc[rf1][cf][r] + bias;
            float g = 0.5f * x * (1.0f + erff(x * 0.70710678118654752f));
            hact[row * 264 + col] = (short)f2bf(g);
        }
    }
    __syncthreads();

    // ---- GEMM2 + exp + weighted partials. Wave wv: heads {2wv,2wv+1},
    //      logit cols [wv*256, wv*256+256). 4 row-groups of 16. ----
    float bias2[16];
#pragma unroll
    for (int cf = 0; cf < 16; ++cf) {
        const int h = 2 * wv + (cf >> 3);
        bias2[cf] = b2[h * 128 + (cf & 7) * 16 + lr];
    }
    float num_acc[16], den_acc[16];
#pragma unroll
    for (int cf = 0; cf < 16; ++cf) { num_acc[cf] = 0.f; den_acc[cf] = 0.f; }

    for (int rf = 0; rf < 4; ++rf) {
        short8 ah0 = *(const short8*)(hact + (rf * 16 + lr) * 264 + (2 * wv + 0) * 32 + lg * 8);
        short8 ah1 = *(const short8*)(hact + (rf * 16 + lr) * 264 + (2 * wv + 1) * 32 + lg * 8);
#pragma unroll
        for (int cf = 0; cf < 16; ++cf) {
            const int h = 2 * wv + (cf >> 3);
            short8 bw = *(const short8*)(w2p + ((size_t)(h * 8 + (cf & 7)) * 64 + lane) * 8);
            f32x4 c = vzero;
            c = __builtin_amdgcn_mfma_f32_16x16x32_bf16((cf < 8) ? ah0 : ah1, bw, c, 0, 0, 0);
            const int col = wv * 256 + (cf >> 3) * 128 + (cf & 7) * 16 + lr;
#pragma unroll
            for (int r = 0; r < 4; ++r) {
                const float e = __expf(c[r] + bias2[cf]);
                const int row = rf * 16 + lg * 4 + r;
                const float f = feat[(m0 + row) * D_ + col];
                den_acc[cf] += e;
                num_acc[cf] = fmaf(f, e, num_acc[cf]);
            }
        }
    }

    // reduce partials over the 4 lg-groups (lanes lr, lr+16, lr+32, lr+48)
    const size_t pb = (size_t)blockIdx.x * 1024;
#pragma unroll
    for (int cf = 0; cf < 16; ++cf) {
        float dn = den_acc[cf];
        dn += __shfl_xor(dn, 16); dn += __shfl_xor(dn, 32);
        float nm = num_acc[cf];
        nm += __shfl_xor(nm, 16); nm += __shfl_xor(nm, 32);
        if (lg == 0) {
            const int col = wv * 256 + (cf >> 3) * 128 + (cf & 7) * 16 + lr;
            pden[pb + col] = dn;
            pnum[pb + col] = nm;
        }
    }
}

// ---------------------------------------------------------------------------
// out[b,d] = sum_j pnum[b*32+j][d] / sum_j pden[b*32+j][d]
__global__ __launch_bounds__(256) void finalize2(
        const float* __restrict__ pnum,
        const float* __restrict__ pden,
        float* __restrict__ out)
{
    const int idx = blockIdx.x * 256 + threadIdx.x;   // 32768 = 32*1024
    const int b = idx >> 10;
    const int d = idx & 1023;
    const size_t base = (size_t)b * 32 * 1024 + d;
    float n = 0.f, dn = 0.f;
#pragma unroll 8
    for (int j = 0; j < 32; ++j) {
        n  += pnum[base + (size_t)j * 1024];
        dn += pden[base + (size_t)j * 1024];
    }
    out[idx] = n / dn;
}

// ---------------------------------------------------------------------------
extern "C" void kernel_launch(void* const* d_in, const int* in_sizes, int n_in,
                              void* d_out, int out_size, void* d_ws, size_t ws_size,
                              hipStream_t stream) {
    (void)in_sizes; (void)n_in; (void)out_size; (void)ws_size;
    const float* feat = (const float*)d_in[0];
    const float* w1   = (const float*)d_in[1];
    const float* b1   = (const float*)d_in[2];
    const float* w2   = (const float*)d_in[3];
    const float* b2   = (const float*)d_in[4];
    float* out = (float*)d_out;

    char* ws = (char*)d_ws;
    float* pnum = (float*)ws;                          // 4 MiB (1024*1024 f32)
    float* pden = (float*)(ws + (4ull << 20));         // 4 MiB
    short* w1p  = (short*)(ws + (8ull << 20));         // 512 KiB
    short* w2p  = (short*)(ws + (8ull << 20) + (512ull << 10));  // 64 KiB

    prep_w1<<<128, 256, 0, stream>>>(w1, w1p);
    prep_w2<<<16, 256, 0, stream>>>(w2, w2p);
    fused1<<<1024, 256, 0, stream>>>(feat, w1p, w2p, b1, b2, pnum, pden);
    finalize2<<<128, 256, 0, stream>>>(pnum, pden, out);
}